// Round 5
// baseline (384.648 us; speedup 1.0000x reference)
//
#include <hip/hip_runtime.h>
#include <hip/hip_bf16.h>

#define NTOT 8192
#define FIN 128
#define FOUT 32
#define NH 4
#define NSEG 4
#define SEGJ (NTOT / NSEG)  // 2048

typedef __attribute__((ext_vector_type(4))) float f32x4;
typedef __attribute__((ext_vector_type(4))) unsigned int u32x4;
typedef __attribute__((ext_vector_type(8))) __bf16 bf16x8;
typedef unsigned long long u64;
typedef unsigned int u32;

__device__ __forceinline__ unsigned short f2bf(float x) {
  __hip_bfloat16 h = __float2bfloat16(x);
  return *reinterpret_cast<unsigned short*>(&h);
}

// ---------------- k0: bit-pack adj -> bits64T[j64][i] (u64 per (row,64j)), 8 MB
__global__ __launch_bounds__(512, 2) void k0_pack(
    const int* __restrict__ adj, u64* __restrict__ bits64T) {
  int row = blockIdx.x * 8 + (threadIdx.x >> 6);
  int l = threadIdx.x & 63;
  const int* ap = adj + (size_t)row * NTOT + l;
  u64* bp = bits64T + row;
#pragma unroll 4
  for (int j64 = 0; j64 < NTOT / 64; ++j64) {
    int v = ap[j64 * 64];
    u64 mske = __ballot(v != 0);
    if (l == 0) bp[(size_t)j64 * NTOT] = mske;
  }
}

// ---------------- k1: h = X @ W -> h [N][128] f32, plus macro-blocked B panels:
// panel[(jt>>1)*8192 + p*1024 + (jt&1)*512 + l*8 + e]  (u16, p = hd*2+half)
//   value = h[node = jt*32 + (l>>4)*8 + e][p*16 + (l&15)]
__global__ __launch_bounds__(256, 2) void k1_project(
    const float* __restrict__ X, const float* __restrict__ W,
    float* __restrict__ h, unsigned short* __restrict__ panel) {
  __shared__ float Xs[32 * 128];
  __shared__ float Ws[32 * 128];
  __shared__ unsigned short Hs[128 * 40];  // [o][node_local], stride 40
  int t = threadIdx.x;
  int nb = blockIdx.x * 32;

  const f32x4* Xg = reinterpret_cast<const f32x4*>(X + (size_t)nb * FIN);
  f32x4* Xs4 = reinterpret_cast<f32x4*>(Xs);
#pragma unroll
  for (int r = 0; r < 4; ++r) Xs4[t + r * 256] = Xg[t + r * 256];

  int ng = t >> 5, oq = t & 31;
  int n0 = ng * 4, o0 = oq * 4;
  f32x4 acc[4];
#pragma unroll
  for (int nn = 0; nn < 4; ++nn) acc[nn] = (f32x4){0.f, 0.f, 0.f, 0.f};

  for (int kp = 0; kp < 4; ++kp) {
    __syncthreads();
#pragma unroll
    for (int r = 0; r < 4; ++r) {
      int q = t + r * 256;
      int flat = q * 4;
      int kk = flat >> 7;
      int c = flat & 127;
      int hdd = c >> 5;
      int oo = c & 31;
      *reinterpret_cast<f32x4*>(&Ws[kk * 128 + c]) =
          *reinterpret_cast<const f32x4*>(W + hdd * (FIN * FOUT) +
                                          (kp * 32 + kk) * FOUT + oo);
    }
    __syncthreads();
#pragma unroll 8
    for (int kk = 0; kk < 32; ++kk) {
      f32x4 wv = *reinterpret_cast<const f32x4*>(&Ws[kk * 128 + o0]);
#pragma unroll
      for (int nn = 0; nn < 4; ++nn)
        acc[nn] += Xs[(n0 + nn) * 128 + kp * 32 + kk] * wv;
    }
  }
#pragma unroll
  for (int nn = 0; nn < 4; ++nn) {
    *reinterpret_cast<f32x4*>(&h[(size_t)(nb + n0 + nn) * 128 + o0]) = acc[nn];
#pragma unroll
    for (int c = 0; c < 4; ++c)
      Hs[(o0 + c) * 40 + (n0 + nn)] = f2bf(acc[nn][c]);
  }
  __syncthreads();
  int jt = blockIdx.x;
#pragma unroll
  for (int it = 0; it < 2; ++it) {
    int item = t + it * 256;
    int p = item >> 6;
    int l = item & 63;
    int o = p * 16 + (l & 15);
    u32x4 v = *reinterpret_cast<const u32x4*>(&Hs[o * 40 + (l >> 4) * 8]);
    *reinterpret_cast<u32x4*>(panel + (size_t)(jt >> 1) * 8192 + p * 1024 +
                              (jt & 1) * 512 + l * 8) = v;
  }
}

// ---------------- k2: per-node score tables for the two-plane scheme
// Sf = s (f32), E1 = exp(s), E2 = exp(.2s) (f32); Dbf = bf16(d),
// F1 = bf16(exp(d)), F2 = bf16(exp(.2d))  — all [hd][N]
__global__ __launch_bounds__(256, 2) void k2_scores(
    const float* __restrict__ h, const float* __restrict__ a_src,
    const float* __restrict__ a_dst, float* __restrict__ Sf,
    float* __restrict__ E1f, float* __restrict__ E2f,
    unsigned short* __restrict__ Dbf, unsigned short* __restrict__ F1bf,
    unsigned short* __restrict__ F2bf) {
  int n = blockIdx.x * 256 + threadIdx.x;
  const f32x4* hv = reinterpret_cast<const f32x4*>(h + (size_t)n * 128);
  const f32x4* as4 = reinterpret_cast<const f32x4*>(a_src);
  const f32x4* ad4 = reinterpret_cast<const f32x4*>(a_dst);
#pragma unroll
  for (int hd = 0; hd < NH; ++hd) {
    f32x4 sa = {0.f, 0.f, 0.f, 0.f}, da = {0.f, 0.f, 0.f, 0.f};
#pragma unroll
    for (int q = 0; q < 8; ++q) {
      f32x4 x = hv[hd * 8 + q];
      sa += x * as4[hd * 8 + q];
      da += x * ad4[hd * 8 + q];
    }
    float s = (sa[0] + sa[1]) + (sa[2] + sa[3]);
    float d = (da[0] + da[1]) + (da[2] + da[3]);
    Sf[hd * NTOT + n] = s;
    E1f[hd * NTOT + n] = expf(s);
    E2f[hd * NTOT + n] = expf(0.2f * s);
    Dbf[hd * NTOT + n] = f2bf(d);
    F1bf[hd * NTOT + n] = f2bf(expf(d));
    F2bf[hd * NTOT + n] = f2bf(expf(0.2f * d));
  }
}

// ---------------- k3: two-plane masked-table MFMA, M=32/wave, LDS panels
__global__ __launch_bounds__(512, 4) void k3_attn(
    const u64* __restrict__ bits64T, const float* __restrict__ Sf,
    const float* __restrict__ E1f, const float* __restrict__ E2f,
    const unsigned short* __restrict__ Dbf,
    const unsigned short* __restrict__ F1bf,
    const unsigned short* __restrict__ F2bf,
    const unsigned short* __restrict__ panel, float* __restrict__ pacc,
    float* __restrict__ plsum) {
  const int N = NTOT;
  __shared__ u32x4 LUTv[256];            // 4 KB: byte -> 4 halfword-mask words
  __shared__ unsigned short panelS[2 * 8192];  // 32 KB double buffer
  int tid = threadIdx.x;
  if (tid < 256) {
    u32x4 e;
#pragma unroll
    for (int q = 0; q < 4; ++q)
      e[q] = (((tid >> (2 * q)) & 1) ? 0xFFFFu : 0u) |
             (((tid >> (2 * q + 1)) & 1) ? 0xFFFF0000u : 0u);
    LUTv[tid] = e;
  }

  int w = tid >> 6, l = tid & 63;
  int hd = w & 3, isub = w >> 2;
  int itile = blockIdx.x >> 2, seg = blockIdx.x & 3;
  int ibase = itile * 64 + isub * 32;
  int m = l & 15, jc = (l >> 4) * 8;
  int i0 = ibase + m, i1 = i0 + 16;
  float sv0 = Sf[hd * N + i0], sv1 = Sf[hd * N + i1];
  int jm0 = seg * 32;

  f32x4 z4 = {0.f, 0.f, 0.f, 0.f};
  f32x4 aP0[2] = {z4, z4}, aP1[2] = {z4, z4};
  f32x4 aN0[2] = {z4, z4}, aN1[2] = {z4, z4};
  f32x4 aPs[2] = {z4, z4}, aNs[2] = {z4, z4};
  bf16x8 bones;
  {
    u32 pat = (m == 0) ? 0x3f803f80u : 0u;
    u32x4 tmp = {pat, pat, pat, pat};
    bones = *reinterpret_cast<bf16x8*>(&tmp);
  }

  u64 TAw0, TAw1, TBw0, TBw1;
  u32x4 TAD[2], TAF1[2], TAF2[2], TBD[2], TBF1[2], TBF2[2];
  u32x4 Pr0, Pr1;

#define K3_LOADT(S, jm_)                                               \
  {                                                                    \
    size_t jmm_ = (size_t)(jm_);                                       \
    S##w0 = bits64T[jmm_ * N + i0];                                    \
    S##w1 = bits64T[jmm_ * N + i1];                                    \
    const unsigned short* db_ = Dbf + hd * N + jmm_ * 64 + jc;         \
    S##D[0] = *(const u32x4*)(db_);                                    \
    S##D[1] = *(const u32x4*)(db_ + 32);                               \
    const unsigned short* f1_ = F1bf + hd * N + jmm_ * 64 + jc;        \
    S##F1[0] = *(const u32x4*)(f1_);                                   \
    S##F1[1] = *(const u32x4*)(f1_ + 32);                              \
    const unsigned short* f2_ = F2bf + hd * N + jmm_ * 64 + jc;        \
    S##F2[0] = *(const u32x4*)(f2_);                                   \
    S##F2[1] = *(const u32x4*)(f2_ + 32);                              \
  }

#define K3_LOADP(jm_)                                                  \
  {                                                                    \
    const unsigned short* pp_ = panel + (size_t)(jm_)*8192 + tid * 8;  \
    Pr0 = *(const u32x4*)(pp_);                                        \
    Pr1 = *(const u32x4*)(pp_ + 4096);                                 \
  }

#define K3_DSW(b_)                                                     \
  {                                                                    \
    *(u32x4*)&panelS[(b_)*8192 + tid * 8] = Pr0;                       \
    *(u32x4*)&panelS[(b_)*8192 + 4096 + tid * 8] = Pr1;                \
  }

#define K3_COMPUTE(S, cur_)                                                    \
  {                                                                            \
    u32 h0_[2] = {(u32)(S##w0), (u32)(S##w0 >> 32)};                           \
    u32 h1_[2] = {(u32)(S##w1), (u32)(S##w1 >> 32)};                           \
    _Pragma("unroll") for (int s = 0; s < 2; ++s) {                            \
      const unsigned short* bp_ =                                              \
          &panelS[(cur_)*8192 + (hd * 2) * 1024 + s * 512 + l * 8];            \
      bf16x8 B0 = *(const bf16x8*)bp_;                                         \
      bf16x8 B1 = *(const bf16x8*)(bp_ + 1024);                                \
      float d_[8];                                                             \
      _Pragma("unroll") for (int p = 0; p < 4; ++p) {                          \
        d_[2 * p] = __uint_as_float(S##D[s][p] << 16);                         \
        d_[2 * p + 1] = __uint_as_float(S##D[s][p] & 0xFFFF0000u);             \
      }                                                                        \
      _Pragma("unroll") for (int rg = 0; rg < 2; ++rg) {                       \
        u32 by_ = ((rg ? h1_[s] : h0_[s]) >> jc) & 0xFFu;                      \
        u32x4 mk_ = LUTv[by_];                                                 \
        float sv_ = rg ? sv1 : sv0;                                            \
        u32 aPw_[4], aNw_[4];                                                  \
        _Pragma("unroll") for (int p = 0; p < 4; ++p) {                        \
          u32 n0_ = (u32)(__float_as_int(sv_ + d_[2 * p]) >> 31);              \
          u32 n1_ = (u32)(__float_as_int(sv_ + d_[2 * p + 1]) >> 31);          \
          u32 mn_ = __builtin_amdgcn_perm(n1_, n0_, 0x05040100u);              \
          aPw_[p] = S##F1[s][p] & (mk_[p] & ~mn_);                             \
          aNw_[p] = S##F2[s][p] & (mk_[p] & mn_);                              \
        }                                                                      \
        bf16x8 afP = *(bf16x8*)aPw_;                                           \
        bf16x8 afN = *(bf16x8*)aNw_;                                           \
        aP0[rg] =                                                              \
            __builtin_amdgcn_mfma_f32_16x16x32_bf16(afP, B0, aP0[rg], 0, 0, 0); \
        aP1[rg] =                                                              \
            __builtin_amdgcn_mfma_f32_16x16x32_bf16(afP, B1, aP1[rg], 0, 0, 0); \
        aN0[rg] =                                                              \
            __builtin_amdgcn_mfma_f32_16x16x32_bf16(afN, B0, aN0[rg], 0, 0, 0); \
        aN1[rg] =                                                              \
            __builtin_amdgcn_mfma_f32_16x16x32_bf16(afN, B1, aN1[rg], 0, 0, 0); \
        aPs[rg] = __builtin_amdgcn_mfma_f32_16x16x32_bf16(afP, bones, aPs[rg],  \
                                                          0, 0, 0);            \
        aNs[rg] = __builtin_amdgcn_mfma_f32_16x16x32_bf16(afN, bones, aNs[rg],  \
                                                          0, 0, 0);            \
      }                                                                        \
    }                                                                          \
  }

  K3_LOADP(jm0 + 0);
  K3_LOADT(TA, jm0 + 0);
  K3_LOADT(TB, jm0 + 1);
  K3_DSW(0);
  K3_LOADP(jm0 + 1);
  __syncthreads();

#pragma unroll 1
  for (int tt = 0; tt < 16; ++tt) {
    int tA = 2 * tt, tB = 2 * tt + 1;
    int nA = tA + 2 > 31 ? 31 : tA + 2;
    int nB = tB + 2 > 31 ? 31 : tB + 2;
    K3_DSW(1);
    K3_LOADP(jm0 + nA);
    K3_COMPUTE(TA, 0);
    K3_LOADT(TA, jm0 + nA);
    __syncthreads();
    K3_DSW(0);
    K3_LOADP(jm0 + nB);
    K3_COMPUTE(TB, 1);
    K3_LOADT(TB, jm0 + nB);
    __syncthreads();
  }
#undef K3_LOADT
#undef K3_LOADP
#undef K3_DSW
#undef K3_COMPUTE

  // epilogue: combine planes with E1/E2; D layout col=lane&15, row=(l>>4)*4+r
#pragma unroll
  for (int rg = 0; rg < 2; ++rg) {
    int rb = ibase + rg * 16 + ((l >> 4) << 2);
    if (m == 0) {
#pragma unroll
      for (int r = 0; r < 4; ++r) {
        int row = rb + r;
        plsum[(seg * NH + hd) * N + row] =
            E1f[hd * N + row] * aPs[rg][r] + E2f[hd * N + row] * aNs[rg][r];
      }
    }
#pragma unroll
    for (int r = 0; r < 4; ++r) {
      int row = rb + r;
      float e1 = E1f[hd * N + row], e2 = E2f[hd * N + row];
      pacc[((size_t)seg * N + row) * 128 + hd * 32 + m] =
          e1 * aP0[rg][r] + e2 * aN0[rg][r];
      pacc[((size_t)seg * N + row) * 128 + hd * 32 + 16 + m] =
          e1 * aP1[rg][r] + e2 * aN1[rg][r];
    }
  }
}

// ---------------- k4: combine segments + normalize
__global__ __launch_bounds__(256, 2) void k4_combine(
    const float* __restrict__ pacc, const float* __restrict__ plsum,
    float* __restrict__ out) {
  int idx = blockIdx.x * 256 + threadIdx.x;
  int i = idx >> 7;
  int c = idx & 127;
  int hd = c >> 5;
  float a = 0.f, ls = 0.f;
#pragma unroll
  for (int s = 0; s < NSEG; ++s) {
    a += pacc[((size_t)s * NTOT + i) * 128 + c];
    ls += plsum[(s * NH + hd) * NTOT + i];
  }
  out[idx] = (ls > 0.f) ? a / ls : 0.f;
}

extern "C" void kernel_launch(void* const* d_in, const int* in_sizes, int n_in,
                              void* d_out, int out_size, void* d_ws,
                              size_t ws_size, hipStream_t stream) {
  const float* X = (const float*)d_in[0];
  const int* adj = (const int*)d_in[1];
  const float* W = (const float*)d_in[2];
  const float* a_src = (const float*)d_in[3];
  const float* a_dst = (const float*)d_in[4];
  float* out = (float*)d_out;

  char* ws = (char*)d_ws;
  float* h = (float*)(ws + 0x0);                             // 4 MB
  unsigned short* panel = (unsigned short*)(ws + 0x400000);  // 2 MB
  float* Sf = (float*)(ws + 0x600000);                       // 128 KB
  float* E1f = (float*)(ws + 0x620000);                      // 128 KB
  float* E2f = (float*)(ws + 0x640000);                      // 128 KB
  unsigned short* Dbf = (unsigned short*)(ws + 0x660000);    // 64 KB
  unsigned short* F1bf = (unsigned short*)(ws + 0x670000);   // 64 KB
  unsigned short* F2bf = (unsigned short*)(ws + 0x680000);   // 64 KB
  u64* bits64T = (u64*)(ws + 0x690000);                      // 8 MB
  float* pacc = (float*)(ws + 0xE90000);                     // 16 MB
  float* plsum = (float*)(ws + 0x1E90000);                   // 512 KB

  k0_pack<<<dim3(1024), dim3(512), 0, stream>>>(adj, bits64T);
  k1_project<<<dim3(256), dim3(256), 0, stream>>>(X, W, h, panel);
  k2_scores<<<dim3(32), dim3(256), 0, stream>>>(h, a_src, a_dst, Sf, E1f, E2f,
                                                Dbf, F1bf, F2bf);
  k3_attn<<<dim3(128 * NSEG), dim3(512), 0, stream>>>(
      bits64T, Sf, E1f, E2f, Dbf, F1bf, F2bf, panel, pacc, plsum);
  k4_combine<<<dim3(4096), dim3(256), 0, stream>>>(pacc, plsum, out);
}

// Round 6
// 187.926 us; speedup vs baseline: 2.0468x; 2.0468x over previous
//
#include <hip/hip_runtime.h>
#include <hip/hip_bf16.h>

#define NTOT 8192
#define FIN 128
#define FOUT 32
#define NH 4
#define NSEG 4
#define SEGJ (NTOT / NSEG)  // 2048
#define LOG2E 1.4426950408889634f

typedef __attribute__((ext_vector_type(4))) float f32x4;
typedef __attribute__((ext_vector_type(4))) unsigned int u32x4;
typedef __attribute__((ext_vector_type(8))) __bf16 bf16x8;
typedef unsigned long long u64;
typedef unsigned int u32;

__device__ __forceinline__ unsigned short f2bf(float x) {
  __hip_bfloat16 h = __float2bfloat16(x);
  return *reinterpret_cast<unsigned short*>(&h);
}

__device__ __forceinline__ float fexp2(float y) {
  float p;
  asm("v_exp_f32 %0, %1" : "=v"(p) : "v"(y));
  return p;
}

// ---------------- k0: bit-pack adj -> bits64T[j64][i] (u64 per (row,64j)), 8 MB
__global__ __launch_bounds__(512, 2) void k0_pack(
    const int* __restrict__ adj, u64* __restrict__ bits64T) {
  int row = blockIdx.x * 8 + (threadIdx.x >> 6);
  int l = threadIdx.x & 63;
  const int* ap = adj + (size_t)row * NTOT + l;
  u64* bp = bits64T + row;
#pragma unroll 4
  for (int j64 = 0; j64 < NTOT / 64; ++j64) {
    int v = ap[j64 * 64];
    u64 mske = __ballot(v != 0);
    if (l == 0) bp[(size_t)j64 * NTOT] = mske;
  }
}

// ---------------- k1: h = X @ W -> h [N][128] f32, plus B-fragment panels:
// panel[(p*256 + jt)*512 + l*8 + e] (bf16), p = hd*2+half,
//   value = h[node = jt*32 + (l>>4)*8 + e][p*16 + (l&15)]
__global__ __launch_bounds__(256, 2) void k1_project(
    const float* __restrict__ X, const float* __restrict__ W,
    float* __restrict__ h, unsigned short* __restrict__ panel) {
  __shared__ float Xs[32 * 128];
  __shared__ float Ws[32 * 128];
  __shared__ unsigned short Hs[128 * 40];  // [o][node_local], stride 40
  int t = threadIdx.x;
  int nb = blockIdx.x * 32;

  const f32x4* Xg = reinterpret_cast<const f32x4*>(X + (size_t)nb * FIN);
  f32x4* Xs4 = reinterpret_cast<f32x4*>(Xs);
#pragma unroll
  for (int r = 0; r < 4; ++r) Xs4[t + r * 256] = Xg[t + r * 256];

  int ng = t >> 5, oq = t & 31;
  int n0 = ng * 4, o0 = oq * 4;
  f32x4 acc[4];
#pragma unroll
  for (int nn = 0; nn < 4; ++nn) acc[nn] = (f32x4){0.f, 0.f, 0.f, 0.f};

  for (int kp = 0; kp < 4; ++kp) {
    __syncthreads();
#pragma unroll
    for (int r = 0; r < 4; ++r) {
      int q = t + r * 256;
      int flat = q * 4;
      int kk = flat >> 7;
      int c = flat & 127;
      int hdd = c >> 5;
      int oo = c & 31;
      *reinterpret_cast<f32x4*>(&Ws[kk * 128 + c]) =
          *reinterpret_cast<const f32x4*>(W + hdd * (FIN * FOUT) +
                                          (kp * 32 + kk) * FOUT + oo);
    }
    __syncthreads();
#pragma unroll 8
    for (int kk = 0; kk < 32; ++kk) {
      f32x4 wv = *reinterpret_cast<const f32x4*>(&Ws[kk * 128 + o0]);
#pragma unroll
      for (int nn = 0; nn < 4; ++nn)
        acc[nn] += Xs[(n0 + nn) * 128 + kp * 32 + kk] * wv;
    }
  }
#pragma unroll
  for (int nn = 0; nn < 4; ++nn) {
    *reinterpret_cast<f32x4*>(&h[(size_t)(nb + n0 + nn) * 128 + o0]) = acc[nn];
#pragma unroll
    for (int c = 0; c < 4; ++c)
      Hs[(o0 + c) * 40 + (n0 + nn)] = f2bf(acc[nn][c]);
  }
  __syncthreads();
  int jt = blockIdx.x;
#pragma unroll
  for (int it = 0; it < 2; ++it) {
    int item = t + it * 256;
    int p = item >> 6;
    int l = item & 63;
    int o = p * 16 + (l & 15);
    u32x4 v = *reinterpret_cast<const u32x4*>(&Hs[o * 40 + (l >> 4) * 8]);
    *reinterpret_cast<u32x4*>(panel + (size_t)(p * 256 + jt) * 512 + l * 8) = v;
  }
}

// ---------------- k2: per-node scores, pre-scaled by log2(e)
__global__ __launch_bounds__(256, 2) void k2_scores(
    const float* __restrict__ h, const float* __restrict__ a_src,
    const float* __restrict__ a_dst, float* __restrict__ Sl2,
    float* __restrict__ Dl2) {
  int n = blockIdx.x * 256 + threadIdx.x;
  const f32x4* hv = reinterpret_cast<const f32x4*>(h + (size_t)n * 128);
  const f32x4* as4 = reinterpret_cast<const f32x4*>(a_src);
  const f32x4* ad4 = reinterpret_cast<const f32x4*>(a_dst);
#pragma unroll
  for (int hd = 0; hd < NH; ++hd) {
    f32x4 sa = {0.f, 0.f, 0.f, 0.f}, da = {0.f, 0.f, 0.f, 0.f};
#pragma unroll
    for (int q = 0; q < 8; ++q) {
      f32x4 x = hv[hd * 8 + q];
      sa += x * as4[hd * 8 + q];
      da += x * ad4[hd * 8 + q];
    }
    float s = (sa[0] + sa[1]) + (sa[2] + sa[3]);
    float d = (da[0] + da[1]) + (da[2] + da[3]);
    Sl2[hd * NTOT + n] = s * LOG2E;
    Dl2[hd * NTOT + n] = d * LOG2E;
  }
}

// ---------------- k3: fused masked softmax + PV. M=32 rows/wave, no LDS,
// in-register adjacency masks, exp2-direct, 2-deep pipeline.
__global__ __launch_bounds__(512, 4) void k3_attn(
    const u64* __restrict__ bits64T, const float* __restrict__ Sl2,
    const float* __restrict__ Dl2, const unsigned short* __restrict__ panel,
    float* __restrict__ pacc, float* __restrict__ plsum) {
  const int N = NTOT;
  int tid = threadIdx.x;
  int w = tid >> 6, l = tid & 63;
  int hd = w & 3, isub = w >> 2;
  int itile = blockIdx.x >> 2, seg = blockIdx.x & 3;
  int ibase = itile * 64 + isub * 32;
  int m = l & 15, jc = (l >> 4) * 8;
  int i0 = ibase + m, i1 = i0 + 16;

  float sv0 = Sl2[hd * N + i0], sv1 = Sl2[hd * N + i1];
  const float* dbase = Dl2 + hd * N + seg * SEGJ + jc;
  const u64* bptr = bits64T + (size_t)(seg * (SEGJ / 64)) * N;
  const unsigned short* pan0 =
      panel + (size_t)((hd * 2 + 0) * 256 + seg * (SEGJ / 32)) * 512 + l * 8;
  const unsigned short* pan1 = pan0 + (size_t)256 * 512;

  f32x4 z4 = {0.f, 0.f, 0.f, 0.f};
  f32x4 acc0[2] = {z4, z4}, acc1[2] = {z4, z4}, acc2[2] = {z4, z4};
  bf16x8 bones;
  {
    u32 pat = (m == 0) ? 0x3f803f80u : 0u;
    u32x4 tmp = {pat, pat, pat, pat};
    bones = *reinterpret_cast<bf16x8*>(&tmp);
  }

#define K3_ISSUE(P, mi_)                                            \
  {                                                                 \
    int mi__ = (mi_);                                               \
    P##w0 = bptr[(size_t)mi__ * N + i0];                            \
    P##w1 = bptr[(size_t)mi__ * N + i1];                            \
    const float* da_ = dbase + mi__ * 64;                           \
    P##d0 = *reinterpret_cast<const f32x4*>(da_);                   \
    P##d1 = *reinterpret_cast<const f32x4*>(da_ + 4);               \
    P##d2 = *reinterpret_cast<const f32x4*>(da_ + 32);              \
    P##d3 = *reinterpret_cast<const f32x4*>(da_ + 36);              \
    const unsigned short* pa_ = pan0 + mi__ * 1024;                 \
    P##p0 = *reinterpret_cast<const bf16x8*>(pa_);                  \
    P##p1 = *reinterpret_cast<const bf16x8*>(pa_ + 512);            \
    const unsigned short* pb_ = pan1 + mi__ * 1024;                 \
    P##q0 = *reinterpret_cast<const bf16x8*>(pb_);                  \
    P##q1 = *reinterpret_cast<const bf16x8*>(pb_ + 512);            \
  }

  // build masked A-frag for one (8-j, row-group): by = adjacency byte
#define K3_AF(AF, BY, DA, DB, SV)                                        \
  {                                                                      \
    f32x4 xa_ = (DA) + (SV);                                             \
    f32x4 xb_ = (DB) + (SV);                                             \
    f32x4 ya_ = __builtin_elementwise_max(xa_, 0.2f * xa_);              \
    f32x4 yb_ = __builtin_elementwise_max(xb_, 0.2f * xb_);              \
    bf16x8 af_;                                                          \
    _Pragma("unroll") for (int e = 0; e < 4; ++e) af_[e] =               \
        (__bf16)fexp2(ya_[e]);                                           \
    _Pragma("unroll") for (int e = 0; e < 4; ++e) af_[e + 4] =           \
        (__bf16)fexp2(yb_[e]);                                           \
    u32x4 mk_;                                                           \
    _Pragma("unroll") for (int p = 0; p < 4; ++p) {                      \
      u32 lo_ = (u32)(((int)((BY) << (31 - 2 * p))) >> 31);              \
      u32 hi_ = (u32)(((int)((BY) << (30 - 2 * p))) >> 31);              \
      mk_[p] = __builtin_amdgcn_perm(hi_, lo_, 0x07060100u);             \
    }                                                                    \
    u32x4 av_ = *reinterpret_cast<u32x4*>(&af_) & mk_;                   \
    AF = *reinterpret_cast<bf16x8*>(&av_);                               \
  }

#define K3_RG(AF, B0, B1, RG)                                                 \
  acc0[RG] = __builtin_amdgcn_mfma_f32_16x16x32_bf16(AF, (B0), acc0[RG], 0,   \
                                                     0, 0);                   \
  acc1[RG] = __builtin_amdgcn_mfma_f32_16x16x32_bf16(AF, (B1), acc1[RG], 0,   \
                                                     0, 0);                   \
  acc2[RG] = __builtin_amdgcn_mfma_f32_16x16x32_bf16(AF, bones, acc2[RG], 0,  \
                                                     0, 0);

#define K3_COMP(P)                                         \
  {                                                        \
    bf16x8 af_r;                                           \
    u32 by_;                                               \
    by_ = ((u32)(P##w0) >> jc) & 0xFFu;                    \
    K3_AF(af_r, by_, P##d0, P##d1, sv0)                    \
    K3_RG(af_r, P##p0, P##q0, 0)                           \
    by_ = ((u32)(P##w1) >> jc) & 0xFFu;                    \
    K3_AF(af_r, by_, P##d0, P##d1, sv1)                    \
    K3_RG(af_r, P##p0, P##q0, 1)                           \
    by_ = ((u32)(P##w0 >> 32) >> jc) & 0xFFu;              \
    K3_AF(af_r, by_, P##d2, P##d3, sv0)                    \
    K3_RG(af_r, P##p1, P##q1, 0)                           \
    by_ = ((u32)(P##w1 >> 32) >> jc) & 0xFFu;              \
    K3_AF(af_r, by_, P##d2, P##d3, sv1)                    \
    K3_RG(af_r, P##p1, P##q1, 1)                           \
  }

  u64 Aw0, Aw1, Bw0, Bw1;
  f32x4 Ad0, Ad1, Ad2, Ad3, Bd0, Bd1, Bd2, Bd3;
  bf16x8 Ap0, Ap1, Aq0, Aq1, Bp0, Bp1, Bq0, Bq1;

  K3_ISSUE(A, 0)
  K3_ISSUE(B, 1)
#pragma unroll 1
  for (int tt = 0; tt < 16; ++tt) {
    int tA = 2 * tt + 2, tB = 2 * tt + 3;
    if (tA > 31) tA = 31;
    if (tB > 31) tB = 31;
    K3_COMP(A)
    K3_ISSUE(A, tA)
    K3_COMP(B)
    K3_ISSUE(B, tB)
  }
#undef K3_ISSUE
#undef K3_AF
#undef K3_RG
#undef K3_COMP

  // epilogue: D layout col=lane&15 (o), row=(lane>>4)*4+reg (i)
#pragma unroll
  for (int rg = 0; rg < 2; ++rg) {
    int rb = ibase + rg * 16 + ((l >> 4) << 2);
    if (m == 0) {
#pragma unroll
      for (int r = 0; r < 4; ++r)
        plsum[(seg * NH + hd) * N + rb + r] = acc2[rg][r];
    }
#pragma unroll
    for (int r = 0; r < 4; ++r) {
      int row = rb + r;
      pacc[((size_t)seg * N + row) * 128 + hd * 32 + m] = acc0[rg][r];
      pacc[((size_t)seg * N + row) * 128 + hd * 32 + 16 + m] = acc1[rg][r];
    }
  }
}

// ---------------- k4: combine segments + normalize
__global__ __launch_bounds__(256, 2) void k4_combine(
    const float* __restrict__ pacc, const float* __restrict__ plsum,
    float* __restrict__ out) {
  int idx = blockIdx.x * 256 + threadIdx.x;
  int i = idx >> 7;
  int c = idx & 127;
  int hd = c >> 5;
  float a = 0.f, ls = 0.f;
#pragma unroll
  for (int s = 0; s < NSEG; ++s) {
    a += pacc[((size_t)s * NTOT + i) * 128 + c];
    ls += plsum[(s * NH + hd) * NTOT + i];
  }
  out[idx] = (ls > 0.f) ? a / ls : 0.f;
}

extern "C" void kernel_launch(void* const* d_in, const int* in_sizes, int n_in,
                              void* d_out, int out_size, void* d_ws,
                              size_t ws_size, hipStream_t stream) {
  const float* X = (const float*)d_in[0];
  const int* adj = (const int*)d_in[1];
  const float* W = (const float*)d_in[2];
  const float* a_src = (const float*)d_in[3];
  const float* a_dst = (const float*)d_in[4];
  float* out = (float*)d_out;

  char* ws = (char*)d_ws;
  float* h = (float*)(ws + 0x0);                             // 4 MB
  unsigned short* panel = (unsigned short*)(ws + 0x400000);  // 2 MB
  float* Sl2 = (float*)(ws + 0x600000);                      // 128 KB
  float* Dl2 = (float*)(ws + 0x620000);                      // 128 KB
  u64* bits64T = (u64*)(ws + 0x640000);                      // 8 MB
  float* pacc = (float*)(ws + 0xE40000);                     // 16 MB
  float* plsum = (float*)(ws + 0x1E40000);                   // 512 KB

  k0_pack<<<dim3(1024), dim3(512), 0, stream>>>(adj, bits64T);
  k1_project<<<dim3(256), dim3(256), 0, stream>>>(X, W, h, panel);
  k2_scores<<<dim3(32), dim3(256), 0, stream>>>(h, a_src, a_dst, Sl2, Dl2);
  k3_attn<<<dim3(128 * NSEG), dim3(512), 0, stream>>>(bits64T, Sl2, Dl2,
                                                      panel, pacc, plsum);
  k4_combine<<<dim3(4096), dim3(256), 0, stream>>>(pacc, plsum, out);
}